// Round 8
// baseline (309.529 us; speedup 1.0000x reference)
//
#include <hip/hip_runtime.h>
#include <hip/hip_bf16.h>
#include <math.h>

// KAN layer, fused v3: block = 128 rows x 256 cols, 8 waves. Per K-step
// (8 dims = 96 halfs): gload_lds B(s+1) into dbuf (piecewise-XOR pre-swizzled
// source, linear dest, swizzled read); featurize(s+1) into padded A dbuf
// (wave = dim -> SGPR params, f32x2 row-pair math); MFMA(s); one barrier.
// y = tanh(F @ W^T + rs*x). No F round-trip through HBM.

#define IN_DIM  512
#define OUT_DIM 512
#define FPI     12
#define KTOT    (IN_DIM * FPI)    // 6144
#define NBATCH  16384

#define PSTRIDE 64
#define WS_WH_OFF_F (PSTRIDE * IN_DIM)   // floats

#define BMF 128
#define BNF 256
#define LDA 104      // padded A stride (halfs)
#define NSTEPS 64    // 512 dims / 8

typedef _Float16 half8 __attribute__((ext_vector_type(8)));
typedef _Float16 half4 __attribute__((ext_vector_type(4)));
typedef float f32x4 __attribute__((ext_vector_type(4)));
typedef float f32x2 __attribute__((ext_vector_type(2)));

__device__ __forceinline__ void gload16(const void* g, void* l) {
    __builtin_amdgcn_global_load_lds((const __attribute__((address_space(1))) void*)g,
                                     (__attribute__((address_space(3))) void*)l, 16, 0, 0);
}

// ---------------- kernel 1: per-dim knots + inverse denominators -----------
__global__ void kan_prep(const float* __restrict__ gsl, const float* __restrict__ gstart,
                         float* __restrict__ P) {
    int i = blockIdx.x * 256 + threadIdx.x;
    if (i >= IN_DIM) return;
    float t[15];
    float a = gstart[i];
    t[0] = a;
#pragma unroll
    for (int m = 0; m < 14; ++m) {
        float z = gsl[i * 14 + m];
        a += fmaxf(z, 0.f) + log1pf(__expf(-fabsf(z)));   // stable softplus
        t[m + 1] = a;
    }
    float* p = P + (size_t)i * PSTRIDE;
#pragma unroll
    for (int m = 0; m < 15; ++m) p[m] = t[m];
#pragma unroll
    for (int m = 0; m < 14; ++m) { float d = t[m+1] - t[m]; p[15+m] = 1.f / ((d == 0.f) ? 1.f : d); }
#pragma unroll
    for (int m = 0; m < 13; ++m) { float d = t[m+2] - t[m]; p[29+m] = 1.f / ((d == 0.f) ? 1.f : d); }
#pragma unroll
    for (int m = 0; m < 12; ++m) { float d = t[m+3] - t[m]; p[42+m] = 1.f / ((d == 0.f) ? 1.f : d); }
#pragma unroll
    for (int m = 54; m < 64; ++m) p[m] = 0.f;
}

// ---------------- kernel 2: pack [coeffs | base_weight] to fp16 ------------
__global__ void kan_packw(const float* __restrict__ coeffs, const float* __restrict__ bw,
                          _Float16* __restrict__ Wh) {
    int idx = blockIdx.x * 256 + threadIdx.x;   // idx = o*512 + i
    const float* src = coeffs + (size_t)idx * 11;
    union { _Float16 h[12]; float2 f2[3]; } u;
#pragma unroll
    for (int c = 0; c < 11; ++c) u.h[c] = (_Float16)src[c];
    u.h[11] = (_Float16)bw[idx];
    float2* dst = (float2*)(Wh + (size_t)idx * FPI);
    dst[0] = u.f2[0]; dst[1] = u.f2[1]; dst[2] = u.f2[2];
}

// ---------------- kernel 3: fused featurize + GEMM + epilogue --------------
__launch_bounds__(512, 2)
__global__ void kan_fused(const float* __restrict__ x, const float* __restrict__ P,
                          const _Float16* __restrict__ Wh, const float* __restrict__ rsp,
                          float* __restrict__ out) {
    __shared__ __align__(16) _Float16 A0[BMF][LDA];    // 26,624 B
    __shared__ __align__(16) _Float16 A1[BMF][LDA];    // 26,624 B
    __shared__ __align__(16) _Float16 B0[BNF * 96];    // 49,152 B
    __shared__ __align__(16) _Float16 B1[BNF * 96];    // 49,152 B -> 151.5 KB total

    const int tid = threadIdx.x;
    const int l = tid & 63;
    const int w = __builtin_amdgcn_readfirstlane(tid >> 6);  // wave 0..7
    const int bid = blockIdx.x;
    const int wg = (bid & 7) * 32 + (bid >> 3);              // XCD swizzle (256 wgs)
    const int rt = wg >> 1, ct = wg & 1;
    const int b0 = rt * BMF, o0 = ct * BNF;

    const int wr = (w >> 2) * 64;      // wave row origin (2 M-groups)
    const int wc = (w & 3) * 64;       // wave col origin (4 N-groups)

    f32x4 acc[4][4];
    const f32x4 zz = {0.f, 0.f, 0.f, 0.f};
#pragma unroll
    for (int m = 0; m < 4; ++m)
#pragma unroll
        for (int n = 0; n < 4; ++n) acc[m][n] = zz;

    // --- B staging: 3072 granules of 16B; thread owns S = j*512+tid.
    // LDS dest linear (S*16); global source granule pre-swizzled per row.
    const char* pB[6];
#pragma unroll
    for (int j = 0; j < 6; ++j) {
        const int S = j * 512 + tid;
        const int row = S / 12, gp = S - row * 12;
        const int g = (gp < 8) ? (gp ^ (row & 7)) : (8 + ((gp - 8) ^ (row & 3)));
        pB[j] = (const char*)(Wh + (size_t)(o0 + row) * KTOT + g * 8);
    }
    // --- swizzled read cols (halfs) per kk: granule = kk*4+h, row&7 = l&7 ---
    const int h = l >> 4;
    int colh[3];
    colh[0] = ((h)     ^ (l & 7)) * 8;
    colh[1] = ((4 + h) ^ (l & 7)) * 8;
    colh[2] = (8 + (h  ^ (l & 3))) * 8;

    const int ar = wr + (l & 15);
    const int koh = h * 8;                 // A col base (halfs) within kk*32
    const int br15 = l & 15;

    // --- featurize x pointers: rows (l, l+64), dim = s*8 + w ---
    const float* xp0 = x + (size_t)(b0 + l) * IN_DIM + w;
    const float* xp1 = x + (size_t)(b0 + l + 64) * IN_DIM + w;

#define FEATURIZE(s, AB)                                                        \
    {                                                                           \
        const float* ps = P + (size_t)((s) * 8 + w) * PSTRIDE;                  \
        f32x2 X = { xv.x, xv.y };                                               \
        f32x2 b[14];                                                            \
        _Pragma("unroll")                                                       \
        for (int m = 0; m < 14; ++m) {                                          \
            float tm = ps[m], tm1 = ps[m + 1];                                  \
            b[m].x = (X.x >= tm && X.x < tm1) ? 1.f : 0.f;                      \
            b[m].y = (X.y >= tm && X.y < tm1) ? 1.f : 0.f;                      \
        }                                                                       \
        _Pragma("unroll")                                                       \
        for (int m = 0; m < 13; ++m) {                                          \
            f32x2 dm = X - ps[m];                                               \
            f32x2 dp = X - ps[m + 2];                                           \
            b[m] = (dm * ps[15 + m]) * b[m] - (dp * ps[16 + m]) * b[m + 1];     \
        }                                                                       \
        _Pragma("unroll")                                                       \
        for (int m = 0; m < 12; ++m) {                                          \
            f32x2 dm = X - ps[m];                                               \
            f32x2 dp = X - ps[m + 3];                                           \
            b[m] = (dm * ps[29 + m]) * b[m] - (dp * ps[30 + m]) * b[m + 1];     \
        }                                                                       \
        _Pragma("unroll")                                                       \
        for (int m = 0; m < 11; ++m) {                                          \
            f32x2 dm = X - ps[m];                                               \
            f32x2 dp = X - ps[m + 4];                                           \
            b[m] = (dm * ps[42 + m]) * b[m] - (dp * ps[43 + m]) * b[m + 1];     \
        }                                                                       \
        f32x2 sil;                                                              \
        sil.x = X.x / (1.f + __expf(-X.x));                                     \
        sil.y = X.y / (1.f + __expf(-X.y));                                     \
        _Pragma("unroll")                                                       \
        for (int pt = 0; pt < 2; ++pt) {                                        \
            const int row = l + pt * 64;                                        \
            half4 h0 = { (_Float16)(pt ? b[0].y : b[0].x),                      \
                         (_Float16)(pt ? b[1].y : b[1].x),                      \
                         (_Float16)(pt ? b[2].y : b[2].x),                      \
                         (_Float16)(pt ? b[3].y : b[3].x) };                    \
            half4 h1 = { (_Float16)(pt ? b[4].y : b[4].x),                      \
                         (_Float16)(pt ? b[5].y : b[5].x),                      \
                         (_Float16)(pt ? b[6].y : b[6].x),                      \
                         (_Float16)(pt ? b[7].y : b[7].x) };                    \
            half4 h2 = { (_Float16)(pt ? b[8].y : b[8].x),                      \
                         (_Float16)(pt ? b[9].y : b[9].x),                      \
                         (_Float16)(pt ? b[10].y : b[10].x),                    \
                         (_Float16)(pt ? sil.y : sil.x) };                      \
            *(half4*)&AB[row][w * 12]     = h0;                                 \
            *(half4*)&AB[row][w * 12 + 4] = h1;                                 \
            *(half4*)&AB[row][w * 12 + 8] = h2;                                 \
        }                                                                       \
    }

#define STEP(s, Ac, Bc, An, Bn)                                                 \
    {                                                                           \
        if ((s) + 1 < NSTEPS) {                                                 \
            _Pragma("unroll")                                                   \
            for (int j = 0; j < 6; ++j)                                         \
                gload16(pB[j] + ((s) + 1) * 192, (char*)Bn + j * 8192 + tid * 16); \
            FEATURIZE((s) + 1, An);                                             \
        }                                                                       \
        if ((s) + 2 < NSTEPS) {                                                 \
            xv2.x = xp0[((s) + 2) * 8]; xv2.y = xp1[((s) + 2) * 8];             \
        }                                                                       \
        _Pragma("unroll")                                                       \
        for (int kk = 0; kk < 3; ++kk) {                                        \
            half8 af[4], bf[4];                                                 \
            _Pragma("unroll")                                                   \
            for (int m = 0; m < 4; ++m)                                         \
                af[m] = *(const half8*)&Ac[ar + m * 16][kk * 32 + koh];         \
            _Pragma("unroll")                                                   \
            for (int n = 0; n < 4; ++n)                                         \
                bf[n] = *(const half8*)&Bc[(wc + n * 16 + br15) * 96 + colh[kk]]; \
            _Pragma("unroll")                                                   \
            for (int m = 0; m < 4; ++m)                                         \
                _Pragma("unroll")                                               \
                for (int n = 0; n < 4; ++n)                                     \
                    acc[m][n] = __builtin_amdgcn_mfma_f32_16x16x32_f16(af[m], bf[n][0] == bf[n][0] ? bf[n] : bf[n], acc[m][n], 0, 0, 0); \
        }                                                                       \
        __syncthreads();                                                        \
        xv = xv2;                                                               \
    }

    // prologue: stage step 0 (B gloads + featurize) into buffer 0
    f32x2 xv, xv2;
    xv.x = xp0[0]; xv.y = xp1[0];
#pragma unroll
    for (int j = 0; j < 6; ++j)
        gload16(pB[j], (char*)B0 + j * 8192 + tid * 16);
    FEATURIZE(0, A0);
    xv.x = xp0[8]; xv.y = xp1[8];
    __syncthreads();

    for (int s = 0; s < NSTEPS; s += 2) {
        STEP(s,     A0, B0, A1, B1);
        STEP(s + 1, A1, B1, A0, B0);
    }

    // ---- epilogue: + rs*x, tanh, store ----
    const float rs = rsp[0];
#pragma unroll
    for (int m = 0; m < 4; ++m)
#pragma unroll
        for (int n = 0; n < 4; ++n)
#pragma unroll
            for (int j = 0; j < 4; ++j) {
                const int r = b0 + wr + m * 16 + (l >> 4) * 4 + j;
                const int c = o0 + wc + n * 16 + (l & 15);
                float v = acc[m][n][j] + rs * x[(size_t)r * IN_DIM + c];
                float e = __expf(2.f * v);            // tanh = 1 - 2/(e^2v+1)
                out[(size_t)r * OUT_DIM + c] = 1.f - 2.f / (e + 1.f);
            }
#undef STEP
#undef FEATURIZE
}

extern "C" void kernel_launch(void* const* d_in, const int* in_sizes, int n_in,
                              void* d_out, int out_size, void* d_ws, size_t ws_size,
                              hipStream_t stream) {
    const float* x      = (const float*)d_in[0];
    const float* coeffs = (const float*)d_in[1];
    const float* bw     = (const float*)d_in[2];
    const float* gsl    = (const float*)d_in[3];
    const float* gstart = (const float*)d_in[4];
    const float* rs     = (const float*)d_in[5];
    float* out = (float*)d_out;
    float* P   = (float*)d_ws;
    _Float16* Wh = (_Float16*)(P + WS_WH_OFF_F);

    kan_prep<<<2, 256, 0, stream>>>(gsl, gstart, P);
    kan_packw<<<1024, 256, 0, stream>>>(coeffs, bw, Wh);
    kan_fused<<<(NBATCH / BMF) * (OUT_DIM / BNF), 512, 0, stream>>>(x, P, Wh, rs, out);
}